// Round 18
// baseline (783.669 us; speedup 1.0000x reference)
//
#include <hip/hip_runtime.h>
#include <hip/hip_cooperative_groups.h>
#include <math.h>

namespace cg = cooperative_groups;

#define BB 256
#define II 2048
#define CC 10
#define DOUT 16
#define COW 160                 // C*DOUT
#define WELEMS (II*CC*DOUT*8)   // 2,621,440 W elements
#define BT 16                   // b per block
#define LEN 64                  // i per block
#define IW 16                   // i per wave (4 i-quads)
#define NSPLIT (II/LEN)         // 32 p-segments

typedef short  short8v __attribute__((ext_vector_type(8)));
typedef float  f32x4   __attribute__((ext_vector_type(4)));

__device__ __forceinline__ ushort f2bf(float x) {   // RNE f32 -> bf16 bits
    union { float f; unsigned u; } v; v.f = x;
    unsigned r = v.u + 0x7fff + ((v.u >> 16) & 1);
    return (ushort)(r >> 16);
}
__device__ __forceinline__ float bf2f(ushort h) {
    union { unsigned u; float f; } v; v.u = ((unsigned)h) << 16; return v.f;
}
__device__ __forceinline__ short8v pack8(float a0, float a1, float a2, float a3,
                                         float b0, float b1, float b2, float b3) {
    short8v r;
    r[0]=(short)f2bf(a0); r[1]=(short)f2bf(a1); r[2]=(short)f2bf(a2); r[3]=(short)f2bf(a3);
    r[4]=(short)f2bf(b0); r[5]=(short)f2bf(b1); r[6]=(short)f2bf(b2); r[7]=(short)f2bf(b3);
    return r;
}

// ---------------- r17-verified route pass body ----------------
template<int MODE>
__device__ __forceinline__ void route_pass(
    const ushort* __restrict__ Wb, const float* __restrict__ vv,
    float* __restrict__ p, const ushort* us, float* red,
    int tid, int bbase, int i0, int ix)
{
    const int l  = tid & 63;
    const int w  = tid >> 6;
    const int bl = l & 15;
    const int g  = l >> 4;
    const int b_abs = bbase + bl;

    float vreg[CC][4];
    if constexpr (MODE >= 1) {
#pragma unroll
        for (int c = 0; c < CC; ++c) {
            const float4 x = *(const float4*)(vv + b_abs * COW + c * DOUT + 4 * g);
            vreg[c][0] = x.x; vreg[c][1] = x.y; vreg[c][2] = x.z; vreg[c][3] = x.w;
        }
    }

    f32x4 acc[CC];
#pragma unroll
    for (int c = 0; c < CC; ++c) acc[c] = (f32x4){0.f, 0.f, 0.f, 0.f};
    const short8v zero8 = {0,0,0,0,0,0,0,0};
    const f32x4   zacc  = (f32x4){0.f, 0.f, 0.f, 0.f};

#pragma unroll
    for (int iq = 0; iq < IW / 4; ++iq) {
        const int ig   = i0 + w * IW + iq * 4;
        const int iloc = w * IW + iq * 4;
        const short8v u8 = *(const short8v*)
            &us[(bl * LEN + ((iloc + g) ^ (bl & 7))) * 8];

        if constexpr (MODE == 0) {
#pragma unroll
            for (int c = 0; c < CC; ++c) {
                const short8v w8 = *(const short8v*)
                    &Wb[((size_t)(ig + g) * CC + c) * 128 + bl * 8];
                acc[c] = __builtin_amdgcn_mfma_f32_16x16x32_bf16(w8, u8, acc[c], 0, 0, 0);
            }
        } else {
            float uf[8];
#pragma unroll
            for (int e = 0; e < 8; ++e) uf[e] = bf2f((ushort)u8[e]);

            float tk[CC];
            short8v w8r[CC];
#pragma unroll
            for (int c = 0; c < CC; ++c) {
                const short8v w8 = *(const short8v*)
                    &Wb[((size_t)(ig + g) * CC + c) * 128 + bl * 8];
                w8r[c] = w8;
                f32x4 uh[4];
#pragma unroll
                for (int j = 0; j < 4; ++j)
                    uh[j] = __builtin_amdgcn_mfma_f32_16x16x32_bf16(
                        w8, (g == j) ? u8 : zero8, zacc, 0, 0, 0);
                float d0 = uh[0][0]*vreg[c][0] + uh[0][1]*vreg[c][1]
                         + uh[0][2]*vreg[c][2] + uh[0][3]*vreg[c][3];
                float d1 = uh[1][0]*vreg[c][0] + uh[1][1]*vreg[c][1]
                         + uh[1][2]*vreg[c][2] + uh[1][3]*vreg[c][3];
                float d2 = uh[2][0]*vreg[c][0] + uh[2][1]*vreg[c][1]
                         + uh[2][2]*vreg[c][2] + uh[2][3]*vreg[c][3];
                float d3 = uh[3][0]*vreg[c][0] + uh[3][1]*vreg[c][1]
                         + uh[3][2]*vreg[c][2] + uh[3][3]*vreg[c][3];
                d0 += __shfl_xor(d0, 16); d0 += __shfl_xor(d0, 32);
                d1 += __shfl_xor(d1, 16); d1 += __shfl_xor(d1, 32);
                d2 += __shfl_xor(d2, 16); d2 += __shfl_xor(d2, 32);
                d3 += __shfl_xor(d3, 16); d3 += __shfl_xor(d3, 32);
                float sel = d0;
                sel = (g == 1) ? d1 : sel;
                sel = (g == 2) ? d2 : sel;
                sel = (g == 3) ? d3 : sel;
                tk[c] = sel;
            }

            float s = 0.f;
#pragma unroll
            for (int c = 0; c < CC; ++c) { tk[c] = __expf(tk[c]); s += tk[c]; }
            const float inv = 1.f / s;

#pragma unroll
            for (int c = 0; c < CC; ++c) {
                const float cw = tk[c] * inv;
                const short8v bfB = pack8(cw*uf[0], cw*uf[1], cw*uf[2], cw*uf[3],
                                          cw*uf[4], cw*uf[5], cw*uf[6], cw*uf[7]);
                acc[c] = __builtin_amdgcn_mfma_f32_16x16x32_bf16(w8r[c], bfB, acc[c], 0, 0, 0);
            }
        }
    }

    // ---- cross-wave reduction -> one p segment per block ----
#pragma unroll
    for (int c = 0; c < CC; ++c)
        *(f32x4*)&red[(((w * CC + c) * 4 + g) * BT + bl) * 4] = acc[c];
    __syncthreads();

    float* pp = p + (size_t)ix * (BB * COW) + (size_t)b_abs * COW;
    for (int c = w * 3; c < CC && c < w * 3 + 3; ++c) {
        f32x4 sacc = (f32x4){0.f, 0.f, 0.f, 0.f};
#pragma unroll
        for (int ww = 0; ww < 4; ++ww) {
            const f32x4 t = *(const f32x4*)&red[(((ww * CC + c) * 4 + g) * BT + bl) * 4];
            sacc[0] += t[0]; sacc[1] += t[1]; sacc[2] += t[2]; sacc[3] += t[3];
        }
        *(float4*)(pp + c * DOUT + 4 * g) =
            make_float4(sacc[0], sacc[1], sacc[2], sacc[3]);
    }
}

// ---------------- r17-verified squash body (grid-wave version) ----------------
__device__ __forceinline__ void squash_pass(
    const float* __restrict__ p, float scale, float* __restrict__ vout,
    const float* __restrict__ vprev, float* __restrict__ vsout,
    int bid, int tid)
{
    const int l   = tid & 63;
    const int o = l & 15, g = l >> 4;
    for (int bc = bid * 4 + (tid >> 6); bc < BB * CC; bc += 2048) {
        const int b = bc / CC, c = bc % CC;
        const float* base = p + (size_t)b * COW + c * DOUT + o;
        float s0 = 0.f, s1 = 0.f;
#pragma unroll
        for (int sp = g; sp < NSPLIT; sp += 8)
            s0 += base[(size_t)sp * (BB * COW)];
#pragma unroll
        for (int sp = g + 4; sp < NSPLIT; sp += 8)
            s1 += base[(size_t)sp * (BB * COW)];
        float s = s0 + s1;
        s += __shfl_xor(s, 16);
        s += __shfl_xor(s, 32);
        s *= scale;
        float sq = s * s;
        sq += __shfl_xor(sq, 1);
        sq += __shfl_xor(sq, 2);
        sq += __shfl_xor(sq, 4);
        sq += __shfl_xor(sq, 8);
        const float sc = (sq / (1.f + sq)) * rsqrtf(sq + 1e-9f);
        if (l < 16) {
            const int idx = b * COW + c * DOUT + o;
            const float v = s * sc;
            vout[idx] = v;
            if (vsout) vsout[idx] = v + vprev[idx];
        }
    }
}

// ---------------- cooperative mega-kernel: all 7 phases ----------------
__global__ __launch_bounds__(256, 2)
void caps_all(const float* __restrict__ u, const float* __restrict__ W,
              ushort* __restrict__ Wb, float* __restrict__ v0,
              float* __restrict__ v1, float* __restrict__ vs,
              float* __restrict__ p, float* __restrict__ out)
{
    __shared__ ushort us[BT * LEN * 8];          // 16 KB, persists ALL passes
    __shared__ float  red[4 * CC * 4 * BT * 4];  // 40 KB

    cg::grid_group grid = cg::this_grid();
    const int tid = threadIdx.x;
    const int ix  = blockIdx.x;                  // i-segment [0,32)
    const int bid = blockIdx.y * gridDim.x + ix; // [0,512)
    const int bbase = blockIdx.y * BT;
    const int i0    = ix * LEN;

    // ---- Phase A: W -> bf16 (grid-strided) + stage this block's u tile ----
    {
        const size_t gsz = (size_t)512 * 256;
        for (size_t e8 = (size_t)bid * 256 + tid; e8 < WELEMS / 8; e8 += gsz) {
            const float4 x0 = *(const float4*)(W + e8 * 8);
            const float4 x1 = *(const float4*)(W + e8 * 8 + 4);
            *(short8v*)(Wb + e8 * 8) = pack8(x0.x, x0.y, x0.z, x0.w,
                                             x1.x, x1.y, x1.z, x1.w);
        }
        for (int e = tid; e < BT * LEN * 2; e += 256) {
            const int rb = e / (LEN * 2), rem = e % (LEN * 2);
            const int i = rem >> 1, dh = (rem & 1) * 4;
            const float4 x = *(const float4*)(u + ((size_t)(bbase + rb) * II + i0 + i) * 8 + dh);
            ushort4 h;
            h.x = f2bf(x.x); h.y = f2bf(x.y); h.z = f2bf(x.z); h.w = f2bf(x.w);
            *(ushort4*)&us[(rb * LEN + (i ^ (rb & 7))) * 8 + dh] = h;
        }
    }
    __threadfence(); grid.sync();

    route_pass<0>(Wb, nullptr, p, us, red, tid, bbase, i0, ix);
    __threadfence(); grid.sync();
    squash_pass(p, 0.1f, v0, nullptr, nullptr, bid, tid);
    __threadfence(); grid.sync();

    route_pass<1>(Wb, v0, p, us, red, tid, bbase, i0, ix);
    __threadfence(); grid.sync();
    squash_pass(p, 1.f, v1, v0, vs, bid, tid);
    __threadfence(); grid.sync();

    route_pass<1>(Wb, vs, p, us, red, tid, bbase, i0, ix);
    __threadfence(); grid.sync();
    squash_pass(p, 1.f, out, nullptr, nullptr, bid, tid);
}

// ================= fallback path (r17-proven, 82 us) =================
__global__ __launch_bounds__(256)
void wcvt(const float* __restrict__ W, ushort* __restrict__ Wb)
{
    const size_t e = ((size_t)blockIdx.x * 256 + threadIdx.x) * 8;
    const float4 x0 = *(const float4*)(W + e);
    const float4 x1 = *(const float4*)(W + e + 4);
    *(short8v*)(Wb + e) = pack8(x0.x, x0.y, x0.z, x0.w, x1.x, x1.y, x1.z, x1.w);
}

template<int MODE>
__global__ __launch_bounds__(256, 2)
void caps_route(const float* __restrict__ u, const ushort* __restrict__ Wb,
                const float* __restrict__ vv, float* __restrict__ p)
{
    __shared__ ushort us[BT * LEN * 8];
    __shared__ float  red[4 * CC * 4 * BT * 4];
    const int tid = threadIdx.x;
    const int bbase = blockIdx.y * BT;
    const int i0    = blockIdx.x * LEN;
    for (int e = tid; e < BT * LEN * 2; e += 256) {
        const int rb = e / (LEN * 2), rem = e % (LEN * 2);
        const int i = rem >> 1, dh = (rem & 1) * 4;
        const float4 x = *(const float4*)(u + ((size_t)(bbase + rb) * II + i0 + i) * 8 + dh);
        ushort4 h;
        h.x = f2bf(x.x); h.y = f2bf(x.y); h.z = f2bf(x.z); h.w = f2bf(x.w);
        *(ushort4*)&us[(rb * LEN + (i ^ (rb & 7))) * 8 + dh] = h;
    }
    __syncthreads();
    route_pass<MODE>(Wb, vv, p, us, red, tid, bbase, i0, blockIdx.x);
}

__global__ __launch_bounds__(64)
void reduce_squash(const float* __restrict__ p, float scale,
                   float* __restrict__ vout, const float* __restrict__ vprev,
                   float* __restrict__ vsout)
{
    const int bc = blockIdx.x;
    const int b = bc / CC, c = bc % CC;
    const int l = threadIdx.x;
    const int o = l & 15, g = l >> 4;
    const float* base = p + (size_t)b * COW + c * DOUT + o;
    float s0 = 0.f, s1 = 0.f;
    for (int sp = g; sp < NSPLIT; sp += 8)
        s0 += base[(size_t)sp * (BB * COW)];
    for (int sp = g + 4; sp < NSPLIT; sp += 8)
        s1 += base[(size_t)sp * (BB * COW)];
    float s = s0 + s1;
    s += __shfl_xor(s, 16);
    s += __shfl_xor(s, 32);
    s *= scale;
    float sq = s * s;
    sq += __shfl_xor(sq, 1);
    sq += __shfl_xor(sq, 2);
    sq += __shfl_xor(sq, 4);
    sq += __shfl_xor(sq, 8);
    const float sc = (sq / (1.f + sq)) * rsqrtf(sq + 1e-9f);
    if (l < 16) {
        const int idx = b * COW + c * DOUT + o;
        const float v = s * sc;
        vout[idx] = v;
        if (vsout) vsout[idx] = v + vprev[idx];
    }
}

extern "C" void kernel_launch(void* const* d_in, const int* in_sizes, int n_in,
                              void* d_out, int out_size, void* d_ws, size_t ws_size,
                              hipStream_t stream)
{
    const float* u = (const float*)d_in[0];   // [256,2048,8]
    const float* W = (const float*)d_in[1];   // [2048,10,16,8]
    float* out = (float*)d_out;               // [256,10,16]

    const size_t SEG = (size_t)BB * COW;      // 40960 floats
    float*  v0 = (float*)d_ws;
    float*  v1 = v0 + SEG;
    float*  vs = v1 + SEG;
    ushort* Wb = (ushort*)(vs + SEG);         // 5.25 MB
    float*  p  = (float*)(Wb + WELEMS);       // NSPLIT * 160KB = 5.25 MB

    // ---- cooperative mega-kernel (single dispatch) ----
    void* kargs[] = { (void*)&u, (void*)&W, (void*)&Wb, (void*)&v0,
                      (void*)&v1, (void*)&vs, (void*)&p, (void*)&out };
    hipError_t err = hipLaunchCooperativeKernel(
        (const void*)caps_all, dim3(NSPLIT, BB / BT), dim3(256, 1, 1),
        kargs, 0, stream);
    if (err == hipSuccess) return;

    // ---- fallback: r17-proven 7-dispatch path ----
    dim3 grid(NSPLIT, BB / BT);
    wcvt<<<WELEMS / (256 * 8), 256, 0, stream>>>(W, Wb);
    caps_route<0><<<grid, 256, 0, stream>>>(u, Wb, nullptr, p);
    reduce_squash<<<BB * CC, 64, 0, stream>>>(p, 0.1f, v0, nullptr, nullptr);
    caps_route<1><<<grid, 256, 0, stream>>>(u, Wb, v0, p);
    reduce_squash<<<BB * CC, 64, 0, stream>>>(p, 1.f, v1, v0, vs);
    caps_route<1><<<grid, 256, 0, stream>>>(u, Wb, vs, p);
    reduce_squash<<<BB * CC, 64, 0, stream>>>(p, 1.f, out, nullptr, nullptr);
}

// Round 19
// 421.896 us; speedup vs baseline: 1.8575x; 1.8575x over previous
//
#include <hip/hip_runtime.h>
#include <math.h>

#define BB 256
#define II 2048
#define CC 10
#define DOUT 16
#define COW 160                 // C*DOUT
#define WELEMS (II*CC*DOUT*8)   // 2,621,440 W elements
#define BT 16                   // b per block
#define LEN 64                  // i per block
#define IW 16                   // i per wave (4 i-quads)
#define NSPLIT (II/LEN)         // 32 p-segments
#define NBLK 512                // route grid = all co-resident (2/CU x 256)

typedef short  short8v __attribute__((ext_vector_type(8)));
typedef float  f32x4   __attribute__((ext_vector_type(4)));

__device__ __forceinline__ ushort f2bf(float x) {   // RNE f32 -> bf16 bits
    union { float f; unsigned u; } v; v.f = x;
    unsigned r = v.u + 0x7fff + ((v.u >> 16) & 1);
    return (ushort)(r >> 16);
}
__device__ __forceinline__ float bf2f(ushort h) {
    union { unsigned u; float f; } v; v.u = ((unsigned)h) << 16; return v.f;
}
__device__ __forceinline__ short8v pack8(float a0, float a1, float a2, float a3,
                                         float b0, float b1, float b2, float b3) {
    short8v r;
    r[0]=(short)f2bf(a0); r[1]=(short)f2bf(a1); r[2]=(short)f2bf(a2); r[3]=(short)f2bf(a3);
    r[4]=(short)f2bf(b0); r[5]=(short)f2bf(b1); r[6]=(short)f2bf(b2); r[7]=(short)f2bf(b3);
    return r;
}

// ---------------- W f32 -> bf16, once ----------------
__global__ __launch_bounds__(256)
void wcvt(const float* __restrict__ W, ushort* __restrict__ Wb)
{
    const size_t e = ((size_t)blockIdx.x * 256 + threadIdx.x) * 8;
    const float4 x0 = *(const float4*)(W + e);
    const float4 x1 = *(const float4*)(W + e + 4);
    *(short8v*)(Wb + e) = pack8(x0.x, x0.y, x0.z, x0.w, x1.x, x1.y, x1.z, x1.w);
}

// ---- inline grid barrier (r18-correctness-proven pattern; all blocks resident)
__device__ __forceinline__ void grid_barrier(unsigned* cnt, int tid)
{
    __threadfence();
    __syncthreads();
    if (tid == 0) {
        atomicAdd(cnt, 1u);
        while (__hip_atomic_load(cnt, __ATOMIC_RELAXED,
                                 __HIP_MEMORY_SCOPE_AGENT) < (unsigned)NBLK)
            __builtin_amdgcn_s_sleep(8);
    }
    __syncthreads();
    __threadfence();
}

// ---------------- fused pass kernel: r17 route body + tail squash ------------
// MODE 0: dense (c_ij uniform; scale=0.1 applied in squash tail).
// MODE 1: routing with v from `vv` (pass1: v0; pass2: vs = v0+v1).
template<int MODE>
__global__ __launch_bounds__(256, 2)
void caps_fused(const float* __restrict__ u, const ushort* __restrict__ Wb,
                const float* __restrict__ vv, float* __restrict__ p,
                float scale, float* __restrict__ vout,
                const float* __restrict__ vprev, float* __restrict__ vsout,
                unsigned* __restrict__ cnt)
{
    __shared__ union {
        ushort us[BT * LEN * 8];                // 16 KB (u tile, bf16)
        float  red[4 * CC * 4 * BT * 4];        // 40 KB [w][c][g][bl][r]
    } sm;

    const int tid = threadIdx.x;
    const int l   = tid & 63;
    const int w   = tid >> 6;        // wave id = i-subrange owner
    const int bl  = l & 15;          // b within tile (B/D col); also A-row o
    const int g   = l >> 4;          // k-group
    const int bbase = blockIdx.y * BT;
    const int b_abs = bbase + bl;
    const int i0    = blockIdx.x * LEN;
    const int bid   = blockIdx.y * gridDim.x + blockIdx.x;

    // ---- stage u -> bf16 LDS (coalesced) ----
    for (int e = tid; e < BT * LEN * 2; e += 256) {
        const int rb = e / (LEN * 2), rem = e % (LEN * 2);
        const int i = rem >> 1, dh = (rem & 1) * 4;
        const float4 x = *(const float4*)(u + ((size_t)(bbase + rb) * II + i0 + i) * 8 + dh);
        ushort4 h;
        h.x = f2bf(x.x); h.y = f2bf(x.y); h.z = f2bf(x.z); h.w = f2bf(x.w);
        *(ushort4*)&sm.us[(rb * LEN + (i ^ (rb & 7))) * 8 + dh] = h;
    }

    // ---- v regs: vreg[c][r] = v[b, c, o=4g+r] ----
    float vreg[CC][4];
    if constexpr (MODE >= 1) {
#pragma unroll
        for (int c = 0; c < CC; ++c) {
            const float4 x = *(const float4*)(vv + b_abs * COW + c * DOUT + 4 * g);
            vreg[c][0] = x.x; vreg[c][1] = x.y; vreg[c][2] = x.z; vreg[c][3] = x.w;
        }
    }

    f32x4 acc[CC];
#pragma unroll
    for (int c = 0; c < CC; ++c) acc[c] = (f32x4){0.f, 0.f, 0.f, 0.f};
    const short8v zero8 = {0,0,0,0,0,0,0,0};
    const f32x4   zacc  = (f32x4){0.f, 0.f, 0.f, 0.f};

    __syncthreads();

#pragma unroll
    for (int iq = 0; iq < IW / 4; ++iq) {
        const int ig   = i0 + w * IW + iq * 4;   // global i base of this quad
        const int iloc = w * IW + iq * 4;        // block-local
        const short8v u8 = *(const short8v*)
            &sm.us[(bl * LEN + ((iloc + g) ^ (bl & 7))) * 8];

        if constexpr (MODE == 0) {
            // ---- dense fold only: acc_c += W * u over the i-quad ----
#pragma unroll
            for (int c = 0; c < CC; ++c) {
                const short8v w8 = *(const short8v*)
                    &Wb[((size_t)(ig + g) * CC + c) * 128 + bl * 8];
                acc[c] = __builtin_amdgcn_mfma_f32_16x16x32_bf16(w8, u8, acc[c], 0, 0, 0);
            }
        } else {
            float uf[8];
#pragma unroll
            for (int e = 0; e < 8; ++e) uf[e] = bf2f((ushort)u8[e]);

            float tk[CC];
            short8v w8r[CC];
            // ---- agreement (round-8-validated) ----
#pragma unroll
            for (int c = 0; c < CC; ++c) {
                const short8v w8 = *(const short8v*)
                    &Wb[((size_t)(ig + g) * CC + c) * 128 + bl * 8];
                w8r[c] = w8;
                f32x4 uh[4];
#pragma unroll
                for (int j = 0; j < 4; ++j)
                    uh[j] = __builtin_amdgcn_mfma_f32_16x16x32_bf16(
                        w8, (g == j) ? u8 : zero8, zacc, 0, 0, 0);
                float d0 = uh[0][0]*vreg[c][0] + uh[0][1]*vreg[c][1]
                         + uh[0][2]*vreg[c][2] + uh[0][3]*vreg[c][3];
                float d1 = uh[1][0]*vreg[c][0] + uh[1][1]*vreg[c][1]
                         + uh[1][2]*vreg[c][2] + uh[1][3]*vreg[c][3];
                float d2 = uh[2][0]*vreg[c][0] + uh[2][1]*vreg[c][1]
                         + uh[2][2]*vreg[c][2] + uh[2][3]*vreg[c][3];
                float d3 = uh[3][0]*vreg[c][0] + uh[3][1]*vreg[c][1]
                         + uh[3][2]*vreg[c][2] + uh[3][3]*vreg[c][3];
                d0 += __shfl_xor(d0, 16); d0 += __shfl_xor(d0, 32);
                d1 += __shfl_xor(d1, 16); d1 += __shfl_xor(d1, 32);
                d2 += __shfl_xor(d2, 16); d2 += __shfl_xor(d2, 32);
                d3 += __shfl_xor(d3, 16); d3 += __shfl_xor(d3, 32);
                float sel = d0;
                sel = (g == 1) ? d1 : sel;
                sel = (g == 2) ? d2 : sel;
                sel = (g == 3) ? d3 : sel;
                tk[c] = sel;               // a[b=bl, i=ig+g, c]
            }

            // ---- softmax over c in regs (|logits| small -> no max-sub) ----
            float s = 0.f;
#pragma unroll
            for (int c = 0; c < CC; ++c) { tk[c] = __expf(tk[c]); s += tk[c]; }
            const float inv = 1.f / s;

            // ---- fold: acc_c += W * (cij .* u), full K over the i-quad ----
#pragma unroll
            for (int c = 0; c < CC; ++c) {
                const float cw = tk[c] * inv;
                const short8v bfB = pack8(cw*uf[0], cw*uf[1], cw*uf[2], cw*uf[3],
                                          cw*uf[4], cw*uf[5], cw*uf[6], cw*uf[7]);
                acc[c] = __builtin_amdgcn_mfma_f32_16x16x32_bf16(w8r[c], bfB, acc[c], 0, 0, 0);
            }
        }
    }

    // ---- cross-wave reduction: 4 waves -> one p segment per block ----
    __syncthreads();                       // all waves done with sm.us
#pragma unroll
    for (int c = 0; c < CC; ++c)
        *(f32x4*)&sm.red[(((w * CC + c) * 4 + g) * BT + bl) * 4] = acc[c];
    __syncthreads();

    float* pp = p + (size_t)blockIdx.x * (BB * COW) + (size_t)b_abs * COW;
    for (int c = w * 3; c < CC && c < w * 3 + 3; ++c) {   // w0:0-2 w1:3-5 w2:6-8 w3:9
        f32x4 sacc = (f32x4){0.f, 0.f, 0.f, 0.f};
#pragma unroll
        for (int ww = 0; ww < 4; ++ww) {
            const f32x4 t = *(const f32x4*)&sm.red[(((ww * CC + c) * 4 + g) * BT + bl) * 4];
            sacc[0] += t[0]; sacc[1] += t[1]; sacc[2] += t[2]; sacc[3] += t[3];
        }
        *(float4*)(pp + c * DOUT + 4 * g) =
            make_float4(sacc[0], sacc[1], sacc[2], sacc[3]);
    }

    // ---- tail: grid barrier, then grid-strided squash (r18-proven body) ----
    grid_barrier(cnt, tid);

    {
        const int o = l & 15, gg = l >> 4;
        for (int bc = bid * 4 + w; bc < BB * CC; bc += 4 * NBLK) {
            const int b = bc / CC, c = bc % CC;
            const float* base = p + (size_t)b * COW + c * DOUT + o;
            float s0 = 0.f, s1 = 0.f;
#pragma unroll
            for (int sp = gg; sp < NSPLIT; sp += 8)
                s0 += base[(size_t)sp * (BB * COW)];
#pragma unroll
            for (int sp = gg + 4; sp < NSPLIT; sp += 8)
                s1 += base[(size_t)sp * (BB * COW)];
            float s = s0 + s1;
            s += __shfl_xor(s, 16);
            s += __shfl_xor(s, 32);
            s *= scale;
            float sq = s * s;
            sq += __shfl_xor(sq, 1);
            sq += __shfl_xor(sq, 2);
            sq += __shfl_xor(sq, 4);
            sq += __shfl_xor(sq, 8);
            const float sc = (sq / (1.f + sq)) * rsqrtf(sq + 1e-9f);
            if (l < 16) {
                const int idx = b * COW + c * DOUT + o;
                const float v = s * sc;
                vout[idx] = v;
                if (vsout) vsout[idx] = v + vprev[idx];
            }
        }
    }
}

extern "C" void kernel_launch(void* const* d_in, const int* in_sizes, int n_in,
                              void* d_out, int out_size, void* d_ws, size_t ws_size,
                              hipStream_t stream)
{
    const float* u = (const float*)d_in[0];   // [256,2048,8]
    const float* W = (const float*)d_in[1];   // [2048,10,16,8]
    float* out = (float*)d_out;               // [256,10,16]

    const size_t SEG = (size_t)BB * COW;      // 40960 floats
    unsigned* cnt = (unsigned*)d_ws;          // 3 counters, 128B apart
    float*  v0 = (float*)d_ws + 128;
    float*  v1 = v0 + SEG;
    float*  vs = v1 + SEG;
    ushort* Wb = (ushort*)(vs + SEG);         // 5.25 MB
    float*  p  = (float*)(Wb + WELEMS);       // NSPLIT * 160KB = 5.25 MB

    hipMemsetAsync(cnt, 0, 128 * sizeof(unsigned), stream);

    dim3 grid(NSPLIT, BB / BT);               // (32, 16) = 512 blocks

    wcvt<<<WELEMS / (256 * 8), 256, 0, stream>>>(W, Wb);
    caps_fused<0><<<grid, 256, 0, stream>>>(u, Wb, nullptr, p,
                                            0.1f, v0, nullptr, nullptr, cnt + 0);
    caps_fused<1><<<grid, 256, 0, stream>>>(u, Wb, v0, p,
                                            1.f, v1, v0, vs, cnt + 32);
    caps_fused<1><<<grid, 256, 0, stream>>>(u, Wb, vs, p,
                                            1.f, out, nullptr, nullptr, cnt + 64);
}

// Round 20
// 105.719 us; speedup vs baseline: 7.4127x; 3.9907x over previous
//
#include <hip/hip_runtime.h>
#include <math.h>

#define BB 256
#define II 2048
#define CC 10
#define DOUT 16
#define COW 160                 // C*DOUT
#define WELEMS (II*CC*DOUT*8)   // 2,621,440 W elements
#define BT 16                   // b per block
#define LEN 128                 // i per block
#define IW 32                   // i per wave (8 i-quads)
#define NSPLIT (II/LEN)         // 16 p-segments

typedef short  short8v __attribute__((ext_vector_type(8)));
typedef float  f32x4   __attribute__((ext_vector_type(4)));

__device__ __forceinline__ ushort f2bf(float x) {   // RNE f32 -> bf16 bits
    union { float f; unsigned u; } v; v.f = x;
    unsigned r = v.u + 0x7fff + ((v.u >> 16) & 1);
    return (ushort)(r >> 16);
}
__device__ __forceinline__ float bf2f(ushort h) {
    union { unsigned u; float f; } v; v.u = ((unsigned)h) << 16; return v.f;
}
__device__ __forceinline__ short8v pack8(float a0, float a1, float a2, float a3,
                                         float b0, float b1, float b2, float b3) {
    short8v r;
    r[0]=(short)f2bf(a0); r[1]=(short)f2bf(a1); r[2]=(short)f2bf(a2); r[3]=(short)f2bf(a3);
    r[4]=(short)f2bf(b0); r[5]=(short)f2bf(b1); r[6]=(short)f2bf(b2); r[7]=(short)f2bf(b3);
    return r;
}

// ---------------- W f32 -> bf16, once ----------------
__global__ __launch_bounds__(256)
void wcvt(const float* __restrict__ W, ushort* __restrict__ Wb)
{
    const size_t e = ((size_t)blockIdx.x * 256 + threadIdx.x) * 8;
    const float4 x0 = *(const float4*)(W + e);
    const float4 x1 = *(const float4*)(W + e + 4);
    *(short8v*)(Wb + e) = pack8(x0.x, x0.y, x0.z, x0.w, x1.x, x1.y, x1.z, x1.w);
}

// ---------------- unified pass kernel (r17-verified body, 1 block/CU) --------
// Block: 16 b x 128 i; wave w owns i in [i0+w*32, i0+w*32+32) (8 i-quads).
// grid = 256 blocks = exactly 1/CU; __launch_bounds__(256,1) frees the
// register allocator (r17's confirmed lever, extended) for deep ILP across
// the 8 independent iq iterations and 10 c-iterations.
// MODE 0: dense (c_ij uniform; 0.1 applied in squash).
// MODE 1: routing with v from `vv` (pass1: v0; pass2: vs = v0+v1).
template<int MODE>
__global__ __launch_bounds__(256, 1)
void caps_route(const float* __restrict__ u, const ushort* __restrict__ Wb,
                const float* __restrict__ vv, float* __restrict__ p)
{
    __shared__ union {
        ushort us[BT * LEN * 8];                // 32 KB (u tile, bf16)
        float  red[4 * CC * 4 * BT * 4];        // 40 KB [w][c][g][bl][r]
    } sm;

    const int tid = threadIdx.x;
    const int l   = tid & 63;
    const int w   = tid >> 6;        // wave id = i-subrange owner
    const int bl  = l & 15;          // b within tile (B/D col); also A-row o
    const int g   = l >> 4;          // k-group
    const int bbase = blockIdx.y * BT;
    const int b_abs = bbase + bl;
    const int i0    = blockIdx.x * LEN;

    // ---- stage u -> bf16 LDS (coalesced) ----
    for (int e = tid; e < BT * LEN * 2; e += 256) {
        const int rb = e / (LEN * 2), rem = e % (LEN * 2);
        const int i = rem >> 1, dh = (rem & 1) * 4;
        const float4 x = *(const float4*)(u + ((size_t)(bbase + rb) * II + i0 + i) * 8 + dh);
        ushort4 h;
        h.x = f2bf(x.x); h.y = f2bf(x.y); h.z = f2bf(x.z); h.w = f2bf(x.w);
        *(ushort4*)&sm.us[(rb * LEN + (i ^ (rb & 7))) * 8 + dh] = h;
    }

    // ---- v regs: vreg[c][r] = v[b, c, o=4g+r] ----
    float vreg[CC][4];
    if constexpr (MODE >= 1) {
#pragma unroll
        for (int c = 0; c < CC; ++c) {
            const float4 x = *(const float4*)(vv + b_abs * COW + c * DOUT + 4 * g);
            vreg[c][0] = x.x; vreg[c][1] = x.y; vreg[c][2] = x.z; vreg[c][3] = x.w;
        }
    }

    f32x4 acc[CC];
#pragma unroll
    for (int c = 0; c < CC; ++c) acc[c] = (f32x4){0.f, 0.f, 0.f, 0.f};
    const short8v zero8 = {0,0,0,0,0,0,0,0};
    const f32x4   zacc  = (f32x4){0.f, 0.f, 0.f, 0.f};

    __syncthreads();

#pragma unroll
    for (int iq = 0; iq < IW / 4; ++iq) {
        const int ig   = i0 + w * IW + iq * 4;   // global i base of this quad
        const int iloc = w * IW + iq * 4;        // block-local
        const short8v u8 = *(const short8v*)
            &sm.us[(bl * LEN + ((iloc + g) ^ (bl & 7))) * 8];

        if constexpr (MODE == 0) {
            // ---- dense fold only: acc_c += W * u over the i-quad ----
#pragma unroll
            for (int c = 0; c < CC; ++c) {
                const short8v w8 = *(const short8v*)
                    &Wb[((size_t)(ig + g) * CC + c) * 128 + bl * 8];
                acc[c] = __builtin_amdgcn_mfma_f32_16x16x32_bf16(w8, u8, acc[c], 0, 0, 0);
            }
        } else {
            float uf[8];
#pragma unroll
            for (int e = 0; e < 8; ++e) uf[e] = bf2f((ushort)u8[e]);

            float tk[CC];
            short8v w8r[CC];
            // ---- agreement (round-8-validated) ----
#pragma unroll
            for (int c = 0; c < CC; ++c) {
                const short8v w8 = *(const short8v*)
                    &Wb[((size_t)(ig + g) * CC + c) * 128 + bl * 8];
                w8r[c] = w8;
                f32x4 uh[4];
#pragma unroll
                for (int j = 0; j < 4; ++j)
                    uh[j] = __builtin_amdgcn_mfma_f32_16x16x32_bf16(
                        w8, (g == j) ? u8 : zero8, zacc, 0, 0, 0);
                float d0 = uh[0][0]*vreg[c][0] + uh[0][1]*vreg[c][1]
                         + uh[0][2]*vreg[c][2] + uh[0][3]*vreg[c][3];
                float d1 = uh[1][0]*vreg[c][0] + uh[1][1]*vreg[c][1]
                         + uh[1][2]*vreg[c][2] + uh[1][3]*vreg[c][3];
                float d2 = uh[2][0]*vreg[c][0] + uh[2][1]*vreg[c][1]
                         + uh[2][2]*vreg[c][2] + uh[2][3]*vreg[c][3];
                float d3 = uh[3][0]*vreg[c][0] + uh[3][1]*vreg[c][1]
                         + uh[3][2]*vreg[c][2] + uh[3][3]*vreg[c][3];
                d0 += __shfl_xor(d0, 16); d0 += __shfl_xor(d0, 32);
                d1 += __shfl_xor(d1, 16); d1 += __shfl_xor(d1, 32);
                d2 += __shfl_xor(d2, 16); d2 += __shfl_xor(d2, 32);
                d3 += __shfl_xor(d3, 16); d3 += __shfl_xor(d3, 32);
                float sel = d0;
                sel = (g == 1) ? d1 : sel;
                sel = (g == 2) ? d2 : sel;
                sel = (g == 3) ? d3 : sel;
                tk[c] = sel;               // a[b=bl, i=ig+g, c]
            }

            // ---- softmax over c in regs (|logits| small -> no max-sub) ----
            float s = 0.f;
#pragma unroll
            for (int c = 0; c < CC; ++c) { tk[c] = __expf(tk[c]); s += tk[c]; }
            const float inv = 1.f / s;

            // ---- fold: acc_c += W * (cij .* u), full K over the i-quad ----
#pragma unroll
            for (int c = 0; c < CC; ++c) {
                const float cw = tk[c] * inv;
                const short8v bfB = pack8(cw*uf[0], cw*uf[1], cw*uf[2], cw*uf[3],
                                          cw*uf[4], cw*uf[5], cw*uf[6], cw*uf[7]);
                acc[c] = __builtin_amdgcn_mfma_f32_16x16x32_bf16(w8r[c], bfB, acc[c], 0, 0, 0);
            }
        }
    }

    // ---- cross-wave reduction: 4 waves -> one p segment per block ----
    __syncthreads();                       // all waves done with sm.us
#pragma unroll
    for (int c = 0; c < CC; ++c)
        *(f32x4*)&sm.red[(((w * CC + c) * 4 + g) * BT + bl) * 4] = acc[c];
    __syncthreads();

    float* pp = p + (size_t)blockIdx.x * (BB * COW) + (size_t)b_abs * COW;
    for (int c = w * 3; c < CC && c < w * 3 + 3; ++c) {   // w0:0-2 w1:3-5 w2:6-8 w3:9
        f32x4 sacc = (f32x4){0.f, 0.f, 0.f, 0.f};
#pragma unroll
        for (int ww = 0; ww < 4; ++ww) {
            const f32x4 t = *(const f32x4*)&sm.red[(((ww * CC + c) * 4 + g) * BT + bl) * 4];
            sacc[0] += t[0]; sacc[1] += t[1]; sacc[2] += t[2]; sacc[3] += t[3];
        }
        *(float4*)(pp + c * DOUT + 4 * g) =
            make_float4(sacc[0], sacc[1], sacc[2], sacc[3]);
    }
}

// one wave per (b,c): sum partials over nsplit segs (2 ILP chains), scale,
// squash -> vout; optionally also write vsout = v + vprev (for pass-3's vs).
__global__ __launch_bounds__(64)
void reduce_squash(const float* __restrict__ p, float scale,
                   float* __restrict__ vout, const float* __restrict__ vprev,
                   float* __restrict__ vsout)
{
    const int bc = blockIdx.x;
    const int b = bc / CC, c = bc % CC;
    const int l = threadIdx.x;
    const int o = l & 15, g = l >> 4;
    const float* base = p + (size_t)b * COW + c * DOUT + o;

    float s0 = 0.f, s1 = 0.f;
#pragma unroll
    for (int sp = g; sp < NSPLIT; sp += 8)
        s0 += base[(size_t)sp * (BB * COW)];
#pragma unroll
    for (int sp = g + 4; sp < NSPLIT; sp += 8)
        s1 += base[(size_t)sp * (BB * COW)];
    float s = s0 + s1;
    s += __shfl_xor(s, 16);
    s += __shfl_xor(s, 32);
    s *= scale;
    float sq = s * s;
    sq += __shfl_xor(sq, 1);
    sq += __shfl_xor(sq, 2);
    sq += __shfl_xor(sq, 4);
    sq += __shfl_xor(sq, 8);
    const float sc = (sq / (1.f + sq)) * rsqrtf(sq + 1e-9f);
    if (l < 16) {
        const int idx = b * COW + c * DOUT + o;
        const float v = s * sc;
        vout[idx] = v;
        if (vsout) vsout[idx] = v + vprev[idx];
    }
}

extern "C" void kernel_launch(void* const* d_in, const int* in_sizes, int n_in,
                              void* d_out, int out_size, void* d_ws, size_t ws_size,
                              hipStream_t stream)
{
    const float* u = (const float*)d_in[0];   // [256,2048,8]
    const float* W = (const float*)d_in[1];   // [2048,10,16,8]
    float* out = (float*)d_out;               // [256,10,16]

    const size_t SEG = (size_t)BB * COW;      // 40960 floats
    float*  v0 = (float*)d_ws;
    float*  v1 = v0 + SEG;
    float*  vs = v1 + SEG;
    ushort* Wb = (ushort*)(vs + SEG);         // 5.25 MB
    float*  p  = (float*)(Wb + WELEMS);       // NSPLIT * 160KB = 2.6 MB

    dim3 grid(NSPLIT, BB / BT);               // (16, 16) = 256 blocks = 1/CU

    wcvt<<<WELEMS / (256 * 8), 256, 0, stream>>>(W, Wb);
    caps_route<0><<<grid, 256, 0, stream>>>(u, Wb, nullptr, p);
    reduce_squash<<<BB * CC, 64, 0, stream>>>(p, 0.1f, v0, nullptr, nullptr);
    caps_route<1><<<grid, 256, 0, stream>>>(u, Wb, v0, p);
    reduce_squash<<<BB * CC, 64, 0, stream>>>(p, 1.f, v1, v0, vs);
    caps_route<1><<<grid, 256, 0, stream>>>(u, Wb, vs, p);
    reduce_squash<<<BB * CC, 64, 0, stream>>>(p, 1.f, out, nullptr, nullptr);
}

// Round 22
// 82.056 us; speedup vs baseline: 9.5504x; 1.2884x over previous
//
#include <hip/hip_runtime.h>
#include <math.h>

#define BB 256
#define II 2048
#define CC 10
#define DOUT 16
#define COW 160                 // C*DOUT
#define WELEMS (II*CC*DOUT*8)   // 2,621,440 W elements
#define BT 16                   // b per block
#define LEN 64                  // i per block
#define IW 16                   // i per wave (4 i-quads)
#define NSPLIT (II/LEN)         // 32 p-segments

typedef short  short8v __attribute__((ext_vector_type(8)));
typedef float  f32x4   __attribute__((ext_vector_type(4)));

__device__ __forceinline__ ushort f2bf(float x) {   // RNE f32 -> bf16 bits
    union { float f; unsigned u; } v; v.f = x;
    unsigned r = v.u + 0x7fff + ((v.u >> 16) & 1);
    return (ushort)(r >> 16);
}
__device__ __forceinline__ float bf2f(ushort h) {
    union { unsigned u; float f; } v; v.u = ((unsigned)h) << 16; return v.f;
}
__device__ __forceinline__ short8v pack8(float a0, float a1, float a2, float a3,
                                         float b0, float b1, float b2, float b3) {
    short8v r;
    r[0]=(short)f2bf(a0); r[1]=(short)f2bf(a1); r[2]=(short)f2bf(a2); r[3]=(short)f2bf(a3);
    r[4]=(short)f2bf(b0); r[5]=(short)f2bf(b1); r[6]=(short)f2bf(b2); r[7]=(short)f2bf(b3);
    return r;
}

// ---------------- W f32 -> bf16, once ----------------
__global__ __launch_bounds__(256)
void wcvt(const float* __restrict__ W, ushort* __restrict__ Wb)
{
    const size_t e = ((size_t)blockIdx.x * 256 + threadIdx.x) * 8;
    const float4 x0 = *(const float4*)(W + e);
    const float4 x1 = *(const float4*)(W + e + 4);
    *(short8v*)(Wb + e) = pack8(x0.x, x0.y, x0.z, x0.w, x1.x, x1.y, x1.z, x1.w);
}

// ---------------- unified pass kernel (r11-verified body) ----------------
// Block: 16 b x 64 i; wave w owns i in [i0+w*16, i0+w*16+16) (4 i-quads).
// MODE 0: dense (c_ij uniform; 0.1 applied in squash).
// MODE 1: routing with v from `vv` (pass1: v0; pass2: vs = v0+v1).
// launch_bounds (256,2): grid (512 blocks) caps residency at 2 blocks/CU
// anyway, so let the register allocator use up to ~256 VGPR for deep
// pipelining of the 10 independent c-iterations and across iq's.
template<int MODE>
__global__ __launch_bounds__(256, 2)
void caps_route(const float* __restrict__ u, const ushort* __restrict__ Wb,
                const float* __restrict__ vv, float* __restrict__ p)
{
    __shared__ union {
        ushort us[BT * LEN * 8];                // 16 KB (u tile, bf16)
        float  red[4 * CC * 4 * BT * 4];        // 40 KB [w][c][g][bl][r]
    } sm;

    const int tid = threadIdx.x;
    const int l   = tid & 63;
    const int w   = tid >> 6;        // wave id = i-subrange owner
    const int bl  = l & 15;          // b within tile (B/D col); also A-row o
    const int g   = l >> 4;          // k-group
    const int bbase = blockIdx.y * BT;
    const int b_abs = bbase + bl;
    const int i0    = blockIdx.x * LEN;

    // ---- stage u -> bf16 LDS (coalesced) ----
    for (int e = tid; e < BT * LEN * 2; e += 256) {
        const int rb = e / (LEN * 2), rem = e % (LEN * 2);
        const int i = rem >> 1, dh = (rem & 1) * 4;
        const float4 x = *(const float4*)(u + ((size_t)(bbase + rb) * II + i0 + i) * 8 + dh);
        ushort4 h;
        h.x = f2bf(x.x); h.y = f2bf(x.y); h.z = f2bf(x.z); h.w = f2bf(x.w);
        *(ushort4*)&sm.us[(rb * LEN + (i ^ (rb & 7))) * 8 + dh] = h;
    }

    // ---- v regs: vreg[c][r] = v[b, c, o=4g+r] ----
    float vreg[CC][4];
    if constexpr (MODE >= 1) {
#pragma unroll
        for (int c = 0; c < CC; ++c) {
            const float4 x = *(const float4*)(vv + b_abs * COW + c * DOUT + 4 * g);
            vreg[c][0] = x.x; vreg[c][1] = x.y; vreg[c][2] = x.z; vreg[c][3] = x.w;
        }
    }

    f32x4 acc[CC];
#pragma unroll
    for (int c = 0; c < CC; ++c) acc[c] = (f32x4){0.f, 0.f, 0.f, 0.f};
    const short8v zero8 = {0,0,0,0,0,0,0,0};
    const f32x4   zacc  = (f32x4){0.f, 0.f, 0.f, 0.f};

    __syncthreads();

#pragma unroll
    for (int iq = 0; iq < IW / 4; ++iq) {
        const int ig   = i0 + w * IW + iq * 4;   // global i base of this quad
        const int iloc = w * IW + iq * 4;        // block-local
        const short8v u8 = *(const short8v*)
            &sm.us[(bl * LEN + ((iloc + g) ^ (bl & 7))) * 8];

        if constexpr (MODE == 0) {
            // ---- dense fold only: acc_c += W * u over the i-quad ----
#pragma unroll
            for (int c = 0; c < CC; ++c) {
                const short8v w8 = *(const short8v*)
                    &Wb[((size_t)(ig + g) * CC + c) * 128 + bl * 8];
                acc[c] = __builtin_amdgcn_mfma_f32_16x16x32_bf16(w8, u8, acc[c], 0, 0, 0);
            }
        } else {
            float uf[8];
#pragma unroll
            for (int e = 0; e < 8; ++e) uf[e] = bf2f((ushort)u8[e]);

            float tk[CC];
            short8v w8r[CC];
            // ---- agreement (round-8-validated) ----
#pragma unroll
            for (int c = 0; c < CC; ++c) {
                const short8v w8 = *(const short8v*)
                    &Wb[((size_t)(ig + g) * CC + c) * 128 + bl * 8];
                w8r[c] = w8;
                f32x4 uh[4];
#pragma unroll
                for (int j = 0; j < 4; ++j)
                    uh[j] = __builtin_amdgcn_mfma_f32_16x16x32_bf16(
                        w8, (g == j) ? u8 : zero8, zacc, 0, 0, 0);
                float d0 = uh[0][0]*vreg[c][0] + uh[0][1]*vreg[c][1]
                         + uh[0][2]*vreg[c][2] + uh[0][3]*vreg[c][3];
                float d1 = uh[1][0]*vreg[c][0] + uh[1][1]*vreg[c][1]
                         + uh[1][2]*vreg[c][2] + uh[1][3]*vreg[c][3];
                float d2 = uh[2][0]*vreg[c][0] + uh[2][1]*vreg[c][1]
                         + uh[2][2]*vreg[c][2] + uh[2][3]*vreg[c][3];
                float d3 = uh[3][0]*vreg[c][0] + uh[3][1]*vreg[c][1]
                         + uh[3][2]*vreg[c][2] + uh[3][3]*vreg[c][3];
                d0 += __shfl_xor(d0, 16); d0 += __shfl_xor(d0, 32);
                d1 += __shfl_xor(d1, 16); d1 += __shfl_xor(d1, 32);
                d2 += __shfl_xor(d2, 16); d2 += __shfl_xor(d2, 32);
                d3 += __shfl_xor(d3, 16); d3 += __shfl_xor(d3, 32);
                float sel = d0;
                sel = (g == 1) ? d1 : sel;
                sel = (g == 2) ? d2 : sel;
                sel = (g == 3) ? d3 : sel;
                tk[c] = sel;               // a[b=bl, i=ig+g, c]
            }

            // ---- softmax over c in regs (|logits| small -> no max-sub) ----
            float s = 0.f;
#pragma unroll
            for (int c = 0; c < CC; ++c) { tk[c] = __expf(tk[c]); s += tk[c]; }
            const float inv = 1.f / s;

            // ---- fold: acc_c += W * (cij .* u), full K over the i-quad ----
#pragma unroll
            for (int c = 0; c < CC; ++c) {
                const float cw = tk[c] * inv;
                const short8v bfB = pack8(cw*uf[0], cw*uf[1], cw*uf[2], cw*uf[3],
                                          cw*uf[4], cw*uf[5], cw*uf[6], cw*uf[7]);
                acc[c] = __builtin_amdgcn_mfma_f32_16x16x32_bf16(w8r[c], bfB, acc[c], 0, 0, 0);
            }
        }
    }

    // ---- cross-wave reduction: 4 waves -> one p segment per block ----
    __syncthreads();                       // all waves done with sm.us
#pragma unroll
    for (int c = 0; c < CC; ++c)
        *(f32x4*)&sm.red[(((w * CC + c) * 4 + g) * BT + bl) * 4] = acc[c];
    __syncthreads();

    float* pp = p + (size_t)blockIdx.x * (BB * COW) + (size_t)b_abs * COW;
    for (int c = w * 3; c < CC && c < w * 3 + 3; ++c) {   // w0:0-2 w1:3-5 w2:6-8 w3:9
        f32x4 sacc = (f32x4){0.f, 0.f, 0.f, 0.f};
#pragma unroll
        for (int ww = 0; ww < 4; ++ww) {
            const f32x4 t = *(const f32x4*)&sm.red[(((ww * CC + c) * 4 + g) * BT + bl) * 4];
            sacc[0] += t[0]; sacc[1] += t[1]; sacc[2] += t[2]; sacc[3] += t[3];
        }
        *(float4*)(pp + c * DOUT + 4 * g) =
            make_float4(sacc[0], sacc[1], sacc[2], sacc[3]);
    }
}

// one wave per (b,c): sum partials over nsplit segs (2 ILP chains), scale,
// squash -> vout; optionally also write vsout = v + vprev (for pass-3's vs).
__global__ __launch_bounds__(64)
void reduce_squash(const float* __restrict__ p, float scale,
                   float* __restrict__ vout, const float* __restrict__ vprev,
                   float* __restrict__ vsout)
{
    const int bc = blockIdx.x;
    const int b = bc / CC, c = bc % CC;
    const int l = threadIdx.x;
    const int o = l & 15, g = l >> 4;
    const float* base = p + (size_t)b * COW + c * DOUT + o;

    float s0 = 0.f, s1 = 0.f;
#pragma unroll
    for (int sp = g; sp < NSPLIT; sp += 8)
        s0 += base[(size_t)sp * (BB * COW)];
#pragma unroll
    for (int sp = g + 4; sp < NSPLIT; sp += 8)
        s1 += base[(size_t)sp * (BB * COW)];
    float s = s0 + s1;
    s += __shfl_xor(s, 16);
    s += __shfl_xor(s, 32);
    s *= scale;
    float sq = s * s;
    sq += __shfl_xor(sq, 1);
    sq += __shfl_xor(sq, 2);
    sq += __shfl_xor(sq, 4);
    sq += __shfl_xor(sq, 8);
    const float sc = (sq / (1.f + sq)) * rsqrtf(sq + 1e-9f);
    if (l < 16) {
        const int idx = b * COW + c * DOUT + o;
        const float v = s * sc;
        vout[idx] = v;
        if (vsout) vsout[idx] = v + vprev[idx];
    }
}

extern "C" void kernel_launch(void* const* d_in, const int* in_sizes, int n_in,
                              void* d_out, int out_size, void* d_ws, size_t ws_size,
                              hipStream_t stream)
{
    const float* u = (const float*)d_in[0];   // [256,2048,8]
    const float* W = (const float*)d_in[1];   // [2048,10,16,8]
    float* out = (float*)d_out;               // [256,10,16]

    const size_t SEG = (size_t)BB * COW;      // 40960 floats
    float*  v0 = (float*)d_ws;
    float*  v1 = v0 + SEG;
    float*  vs = v1 + SEG;
    ushort* Wb = (ushort*)(vs + SEG);         // 5.25 MB
    float*  p  = (float*)(Wb + WELEMS);       // NSPLIT * 160KB = 5.25 MB

    dim3 grid(NSPLIT, BB / BT);               // (32, 16) = 512 blocks

    wcvt<<<WELEMS / (256 * 8), 256, 0, stream>>>(W, Wb);
    caps_route<0><<<grid, 256, 0, stream>>>(u, Wb, nullptr, p);
    reduce_squash<<<BB * CC, 64, 0, stream>>>(p, 0.1f, v0, nullptr, nullptr);
    caps_route<1><<<grid, 256, 0, stream>>>(u, Wb, v0, p);
    reduce_squash<<<BB * CC, 64, 0, stream>>>(p, 1.f, v1, v0, vs);
    caps_route<1><<<grid, 256, 0, stream>>>(u, Wb, vs, p);
    reduce_squash<<<BB * CC, 64, 0, stream>>>(p, 1.f, out, nullptr, nullptr);
}